// Round 10
// baseline (135.235 us; speedup 1.0000x reference)
//
#include <hip/hip_runtime.h>

// MultiHeadAttention: B=2, S=4096, E=512, H=8, D=64
// cvt(fp32->bf16, float4) -> QKV gemm (q pre-scaled by log2e/sqrt(512)) ->
// flash attention (8 waves, 32x32x16 MFMA, superrow-swizzled K/V LDS,
//                  in-register P via cvtpk+permlane32_swap, fixed-shift softmax,
//                  VALU row-sum, persistent-zero et init, dbuf) ->
// out-proj gemm (64x128 tile, 512 blocks) -> fp32 out.

typedef __bf16 bf16x8 __attribute__((ext_vector_type(8)));
typedef float f32x4 __attribute__((ext_vector_type(4)));
typedef float f32x16 __attribute__((ext_vector_type(16)));
typedef unsigned int u32x4 __attribute__((ext_vector_type(4)));
typedef unsigned short u16x4 __attribute__((ext_vector_type(4)));

union U8 { bf16x8 b; u32x4 q; unsigned short s[8]; };

__device__ __forceinline__ unsigned short f2bf(float f) {
    union { float f; unsigned u; } x; x.f = f;
    unsigned r = x.u + 0x7FFFu + ((x.u >> 16) & 1u);   // RNE
    return (unsigned short)(r >> 16);
}

// packed f32x2 -> bf16x2 (lo -> D[15:0], hi -> D[31:16]) — order verified by R2/R3 pass
__device__ __forceinline__ unsigned cvtpk(float lo, float hi) {
    unsigned d;
    asm("v_cvt_pk_bf16_f32 %0, %1, %2" : "=v"(d) : "v"(lo), "v"(hi));
    return d;
}

#if __has_builtin(__builtin_amdgcn_exp2f)
__device__ __forceinline__ float hexp2(float x) { return __builtin_amdgcn_exp2f(x); }
#else
__device__ __forceinline__ float hexp2(float x) { return exp2f(x); }
#endif

// async global->LDS, 16B per lane. LDS dest is wave-uniform base; HW adds lane*16.
__device__ __forceinline__ void stage16(const void* g, void* lds) {
    __builtin_amdgcn_global_load_lds(
        (const __attribute__((address_space(1))) unsigned*)g,
        (__attribute__((address_space(3))) unsigned*)lds, 16, 0, 0);
}

__device__ __forceinline__ f32x4 mfma16(bf16x8 a, bf16x8 b, f32x4 c) {
    return __builtin_amdgcn_mfma_f32_16x16x32_bf16(a, b, c, 0, 0, 0);
}
__device__ __forceinline__ f32x16 mfma32(bf16x8 a, bf16x8 b, f32x16 c) {
    return __builtin_amdgcn_mfma_f32_32x32x16_bf16(a, b, c, 0, 0, 0);
}

// ---------------- convert fp32 -> bf16 (x, Wq|Wk|Wv packed, Wo), float4 ----------------
__global__ __launch_bounds__(256) void cvt_kernel(
    const float* __restrict__ x, const float* __restrict__ wq, const float* __restrict__ wk,
    const float* __restrict__ wv, const float* __restrict__ wo,
    unsigned short* __restrict__ xb, unsigned short* __restrict__ wqkv,
    unsigned short* __restrict__ wob)
{
    const int NX = 8192 * 512 / 4, NW = 512 * 512 / 4;   // in float4 units
    const int total = NX + 4 * NW;
    for (int i = blockIdx.x * 256 + threadIdx.x; i < total; i += gridDim.x * 256) {
        float4 v; unsigned short* dst;
        if (i < NX) {
            v = ((const float4*)x)[i]; dst = xb + i * 4;
        } else if (i < NX + 3 * NW) {
            int j = i - NX; int p = j / NW; int r = j - p * NW;
            const float* w = (p == 0) ? wq : (p == 1) ? wk : wv;
            v = ((const float4*)w)[r]; dst = wqkv + j * 4;
        } else {
            int j = i - NX - 3 * NW;
            v = ((const float4*)wo)[j]; dst = wob + j * 4;
        }
        u16x4 o;
        o.x = f2bf(v.x); o.y = f2bf(v.y); o.z = f2bf(v.z); o.w = f2bf(v.w);
        *(u16x4*)dst = o;
    }
}

// ---------------- QKV GEMM C = A @ Bw^T (+bias); A:[8192][512], Bw:[1536][512] bf16 ----------------
// scatter: q (pre-scaled by log2e/sqrt(512)) [bh][s][d], k [bh][s][d], vt [bh][d][s]
__global__ __launch_bounds__(256) void gemm_bt(
    const unsigned short* __restrict__ A, const unsigned short* __restrict__ Bw,
    const float* __restrict__ bias0, const float* __restrict__ bias1, const float* __restrict__ bias2,
    unsigned short* __restrict__ qo, unsigned short* __restrict__ ko, unsigned short* __restrict__ vto)
{
    __shared__ unsigned short Al[128 * 64];
    __shared__ unsigned short Bl[128 * 64];
    const int tid = threadIdx.x;
    const int l = tid & 63, w = tid >> 6;
    const int l15 = l & 15, g = l >> 4;
    const int m0 = blockIdx.y * 128, n0 = blockIdx.x * 128;
    const int mo = (w >> 1) * 64, no = (w & 1) * 64;
    f32x4 acc[4][4] = {};

    for (int k0 = 0; k0 < 512; k0 += 64) {
        __syncthreads();
        #pragma unroll
        for (int i = 0; i < 4; ++i) {
            int off = i * 4096 + w * 1024 + l * 16;
            int row = off >> 7;
            int c = (l & 7) ^ (row & 7);
            stage16(A + (m0 + row) * 512 + k0 + c * 8, (char*)Al + i * 4096 + w * 1024);
            stage16(Bw + (n0 + row) * 512 + k0 + c * 8, (char*)Bl + i * 4096 + w * 1024);
        }
        __syncthreads();
        #pragma unroll
        for (int ks = 0; ks < 2; ++ks) {
            U8 af[4];
            #pragma unroll
            for (int mt = 0; mt < 4; ++mt) {
                int row = mo + mt * 16 + l15;
                int c = (ks * 4 + g) ^ (row & 7);
                af[mt].q = *(const u32x4*)((const char*)Al + row * 128 + c * 16);
            }
            #pragma unroll
            for (int nt = 0; nt < 4; ++nt) {
                int row = no + nt * 16 + l15;
                int c = (ks * 4 + g) ^ (row & 7);
                U8 bf; bf.q = *(const u32x4*)((const char*)Bl + row * 128 + c * 16);
                #pragma unroll
                for (int mt = 0; mt < 4; ++mt)
                    acc[mt][nt] = mfma16(af[mt].b, bf.b, acc[mt][nt]);
            }
        }
    }

    const float QSC = 0.06375871897178588f;      // log2(e)/sqrt(512)
    #pragma unroll
    for (int nt = 0; nt < 4; ++nt) {
        int n = n0 + no + nt * 16 + l15;
        int proj = n >> 9, nn = n & 511;
        int h = nn >> 6, d = nn & 63;
        const float* bp = (proj == 0) ? bias0 : (proj == 1) ? bias1 : bias2;
        float bv_ = bp[nn];
        #pragma unroll
        for (int mt = 0; mt < 4; ++mt) {
            int m = m0 + mo + mt * 16 + g * 4;
            int bb = m >> 12, s = m & 4095;
            if (proj == 0) {
                unsigned short* dst = qo + ((bb * 8 + h) * 4096 + s) * 64 + d;
                #pragma unroll
                for (int r = 0; r < 4; ++r)
                    dst[r * 64] = f2bf((acc[mt][nt][r] + bv_) * QSC);
            } else if (proj == 1) {
                unsigned short* dst = ko + ((bb * 8 + h) * 4096 + s) * 64 + d;
                #pragma unroll
                for (int r = 0; r < 4; ++r)
                    dst[r * 64] = f2bf(acc[mt][nt][r] + bv_);
            } else {
                u16x4 v4;
                v4.x = f2bf(acc[mt][nt][0] + bv_);
                v4.y = f2bf(acc[mt][nt][1] + bv_);
                v4.z = f2bf(acc[mt][nt][2] + bv_);
                v4.w = f2bf(acc[mt][nt][3] + bv_);
                *(u16x4*)(vto + ((bb * 8 + h) * 64 + d) * 4096 + s) = v4;
            }
        }
    }
}

// ---------------- out-proj GEMM: out = ao @ Wo^T + bo; 64x128 tile, grid 4x128 ----------------
__global__ __launch_bounds__(256) void gemm_o(
    const unsigned short* __restrict__ A, const unsigned short* __restrict__ Bw,
    const float* __restrict__ bias, float* __restrict__ outf)
{
    __shared__ unsigned short Al[64 * 64];    // 8KB
    __shared__ unsigned short Bl[128 * 64];   // 16KB
    const int tid = threadIdx.x;
    const int l = tid & 63, w = tid >> 6;
    const int l15 = l & 15, g = l >> 4;
    const int m0 = blockIdx.y * 64, n0 = blockIdx.x * 128;
    const int mo = (w >> 1) * 32, no = (w & 1) * 64;
    f32x4 acc[2][4] = {};

    for (int k0 = 0; k0 < 512; k0 += 64) {
        __syncthreads();
        #pragma unroll
        for (int i = 0; i < 2; ++i) {
            int jj = w * 2 + i;
            int off = jj * 1024 + l * 16;
            int row = off >> 7;
            int c = (l & 7) ^ (row & 7);
            stage16(A + (m0 + row) * 512 + k0 + c * 8, (char*)Al + jj * 1024);
        }
        #pragma unroll
        for (int i = 0; i < 4; ++i) {
            int jj = w * 4 + i;
            int off = jj * 1024 + l * 16;
            int row = off >> 7;
            int c = (l & 7) ^ (row & 7);
            stage16(Bw + (n0 + row) * 512 + k0 + c * 8, (char*)Bl + jj * 1024);
        }
        __syncthreads();
        #pragma unroll
        for (int ks = 0; ks < 2; ++ks) {
            U8 af[2];
            #pragma unroll
            for (int mt = 0; mt < 2; ++mt) {
                int row = mo + mt * 16 + l15;
                int c = (ks * 4 + g) ^ (row & 7);
                af[mt].q = *(const u32x4*)((const char*)Al + row * 128 + c * 16);
            }
            #pragma unroll
            for (int nt = 0; nt < 4; ++nt) {
                int row = no + nt * 16 + l15;
                int c = (ks * 4 + g) ^ (row & 7);
                U8 bf; bf.q = *(const u32x4*)((const char*)Bl + row * 128 + c * 16);
                #pragma unroll
                for (int mt = 0; mt < 2; ++mt)
                    acc[mt][nt] = mfma16(af[mt].b, bf.b, acc[mt][nt]);
            }
        }
    }
    #pragma unroll
    for (int nt = 0; nt < 4; ++nt) {
        int n = n0 + no + nt * 16 + l15;
        float bv_ = bias[n];
        #pragma unroll
        for (int mt = 0; mt < 2; ++mt) {
            int m = m0 + mo + mt * 16 + g * 4;
            float* dst = outf + (size_t)m * 512 + n;
            #pragma unroll
            for (int r = 0; r < 4; ++r)
                dst[(size_t)r * 512] = acc[mt][nt][r] + bv_;
        }
    }
}

// ---------------- flash attention: 8 waves, 32x32x16, superrow-swizzled LDS ----------------
// grid 512. wave w: half hb=w>>2 (KV range [hb*2048,+2048)), q-group w4=w&3 (32 q-rows).
// LDS per parity per half: [K 8KB][V 8KB]; 2 parities x 2 halves = 64KB.
// Tile [64 rows][128B]; swizzle: s_phys = ((row&1)*8 + chunkcol) ^ ((row>>1)&15),
// same involution on stage-source and read -> conflict-free b128 (verified R6: 65K conflicts).
// P pack via cvtpk+permlane32_swap (verified R3). Fixed-shift softmax (m==0, verified R8).
// Row-sum via VALU adds hidden under PV MFMA (R8-proven; R9's ones-MFMA was 2us slower).
// et accumulators init from a persistent FZERO (no per-chunk v_accvgpr zero writes).
__global__ __launch_bounds__(512, 4) void attn_kernel(
    const unsigned short* __restrict__ Qg, const unsigned short* __restrict__ Kg,
    const unsigned short* __restrict__ Vtg, unsigned short* __restrict__ Og)
{
    __shared__ __align__(16) char ldsb[65536];
    const int tid = threadIdx.x;
    const int l = tid & 63, w = tid >> 6;
    const int l31 = l & 31, hi = l >> 5;
    const int hb = w >> 2, w4 = w & 3;

    // XCD swizzle: 2 whole heads per XCD.
    const int xcd = blockIdx.x & 7, idx = blockIdx.x >> 3;
    const int bh = xcd * 2 + (idx >> 5), qb = idx & 31;

    const unsigned short* qh = Qg + bh * 4096 * 64;
    const char* khb = (const char*)(Kg + (size_t)bh * 4096 * 64);
    const char* vhb = (const char*)(Vtg + (size_t)bh * 64 * 4096);
    const int qw = qb * 128 + w4 * 32;

    // Q B-frags (log2-domain pre-scaled): Qf[ds] elem i = Q[qw+l31][ds*16 + 8*hi + i]
    U8 Qf[4];
    #pragma unroll
    for (int ds_ = 0; ds_ < 4; ++ds_)
        Qf[ds_].q = *(const u32x4*)(qh + (qw + l31) * 64 + ds_ * 16 + hi * 8);

    // persistent zero accumulator (et first-MFMA C-operand; never written after init)
    f32x16 FZERO = {};
    asm volatile("" : "+v"(FZERO));   // pin: prevent folding back into per-chunk zero-init

    // frag-read lane offsets (same formula for K and V): frag row = base32 + l31,
    // chunk-col = 2*j + hi; superrow R = (row>>1), swizzled slot, +hb tile select.
    int rd[4];
    #pragma unroll
    for (int j = 0; j < 4; ++j) {
        int sl = ((l31 & 1) << 3) + j * 2 + hi;
        int sp = sl ^ (l31 >> 1);
        rd[j] = hb * 16384 + (l31 >> 1) * 256 + sp * 16;
    }

    // stage source pointers: lane covers LDS tile byte q = jj*1024 + l*16.
    // decode: R=q>>8, sp=(q>>4)&15, sl=sp^(R&15), row=2R+(sl>>3), c=sl&7
    const char* ksrc0; const char* ksrc1; const char* vsrc0; const char* vsrc1;
    {
        int q0 = (w4 * 2 + 0) * 1024 + l * 16;
        int q1 = (w4 * 2 + 1) * 1024 + l * 16;
        int R0 = q0 >> 8, sl0 = ((q0 >> 4) & 15) ^ (R0 & 15);
        int R1 = q1 >> 8, sl1 = ((q1 >> 4) & 15) ^ (R1 & 15);
        int row0 = 2 * R0 + (sl0 >> 3), c0 = sl0 & 7;
        int row1 = 2 * R1 + (sl1 >> 3), c1 = sl1 & 7;
        ksrc0 = khb + (size_t)(hb * 2048 + row0) * 128 + c0 * 16;
        ksrc1 = khb + (size_t)(hb * 2048 + row1) * 128 + c1 * 16;
        vsrc0 = vhb + (size_t)row0 * 8192 + hb * 4096 + c0 * 16;
        vsrc1 = vhb + (size_t)row1 * 8192 + hb * 4096 + c1 * 16;
    }

    f32x16 oacc[2] = {};   // [dt] : O^T[d = dt*32 + crow][q = l31]
    float lrun = 0.f;      // own-half partial row-sum (shift m==0)

    // prologue: stage chunk 0 into parity-0 buffers
    stage16(ksrc0, ldsb + hb * 16384 + (w4 * 2 + 0) * 1024);
    stage16(ksrc1, ldsb + hb * 16384 + (w4 * 2 + 1) * 1024);
    stage16(vsrc0, ldsb + hb * 16384 + 8192 + (w4 * 2 + 0) * 1024);
    stage16(vsrc1, ldsb + hb * 16384 + 8192 + (w4 * 2 + 1) * 1024);
    ksrc0 += 8192; ksrc1 += 8192; vsrc0 += 128; vsrc1 += 128;
    __syncthreads();

#define CHUNK(T_, PAR_) {                                                          \
    if ((T_) != 31) {                                                              \
        stage16(ksrc0, ldsb + (1 - (PAR_)) * 32768 + hb * 16384 + (w4 * 2 + 0) * 1024); \
        stage16(ksrc1, ldsb + (1 - (PAR_)) * 32768 + hb * 16384 + (w4 * 2 + 1) * 1024); \
        stage16(vsrc0, ldsb + (1 - (PAR_)) * 32768 + hb * 16384 + 8192 + (w4 * 2 + 0) * 1024); \
        stage16(vsrc1, ldsb + (1 - (PAR_)) * 32768 + hb * 16384 + 8192 + (w4 * 2 + 1) * 1024); \
    }                                                                              \
    ksrc0 += 8192; ksrc1 += 8192; vsrc0 += 128; vsrc1 += 128;                      \
    f32x16 et[2];                                                                  \
    __builtin_amdgcn_s_setprio(1);                                                 \
    {                                                                              \
        U8 kf0, kf1;                                                               \
        kf0.q = *(const u32x4*)(ldsb + (PAR_) * 32768 + rd[0]);                    \
        kf1.q = *(const u32x4*)(ldsb + (PAR_) * 32768 + 4096 + rd[0]);             \
        et[0] = mfma32(kf0.b, Qf[0].b, FZERO);                                     \
        et[1] = mfma32(kf1.b, Qf[0].b, FZERO);                                     \
    }                                                                              \
    _Pragma("unroll")                                                              \
    for (int ds_ = 1; ds_ < 4; ++ds_) {                                            \
        U8 kf0, kf1;                                                               \
        kf0.q = *(const u32x4*)(ldsb + (PAR_) * 32768 + rd[ds_]);                  \
        kf1.q = *(const u32x4*)(ldsb + (PAR_) * 32768 + 4096 + rd[ds_]);           \
        et[0] = mfma32(kf0.b, Qf[ds_].b, et[0]);                                   \
        et[1] = mfma32(kf1.b, Qf[ds_].b, et[1]);                                   \
    }                                                                              \
    __builtin_amdgcn_s_setprio(0);                                                 \
    float rs = 0.f;                                                                \
    _Pragma("unroll")                                                              \
    for (int ks = 0; ks < 4; ++ks) {                                               \
        const int mt_ = ks >> 1, r0_ = (ks & 1) * 8;                               \
        U8 vf0, vf1;   /* independent of pack: issue first, hide DS latency */     \
        vf0.q = *(const u32x4*)(ldsb + (PAR_) * 32768 + 8192 + rd[ks]);            \
        vf1.q = *(const u32x4*)(ldsb + (PAR_) * 32768 + 8192 + 4096 + rd[ks]);     \
        float p0 = hexp2(et[mt_][r0_ + 0]);                                        \
        float p1 = hexp2(et[mt_][r0_ + 1]);                                        \
        float p2 = hexp2(et[mt_][r0_ + 2]);                                        \
        float p3 = hexp2(et[mt_][r0_ + 3]);                                        \
        float p4 = hexp2(et[mt_][r0_ + 4]);                                        \
        float p5 = hexp2(et[mt_][r0_ + 5]);                                        \
        float p6 = hexp2(et[mt_][r0_ + 6]);                                        \
        float p7 = hexp2(et[mt_][r0_ + 7]);                                        \
        rs += ((p0 + p1) + (p2 + p3)) + ((p4 + p5) + (p6 + p7));                   \
        unsigned X0 = cvtpk(p0, p1), X1 = cvtpk(p2, p3);                           \
        unsigned Y0 = cvtpk(p4, p5), Y1 = cvtpk(p6, p7);                           \
        asm volatile("v_permlane32_swap_b32 %0, %1" : "+v"(X0), "+v"(Y0));         \
        asm volatile("v_permlane32_swap_b32 %0, %1" : "+v"(X1), "+v"(Y1));         \
        U8 pb_; pb_.q.x = X0; pb_.q.y = X1; pb_.q.z = Y0; pb_.q.w = Y1;            \
        __builtin_amdgcn_s_setprio(1);                                             \
        oacc[0] = mfma32(vf0.b, pb_.b, oacc[0]);                                   \
        oacc[1] = mfma32(vf1.b, pb_.b, oacc[1]);                                   \
        __builtin_amdgcn_s_setprio(0);                                             \
    }                                                                              \
    lrun += rs;   /* own-half partial; cross-half summed after loop */             \
    __syncthreads();                                                               \
}

    #pragma unroll 1
    for (int t2 = 0; t2 < 16; ++t2) {
        CHUNK(2 * t2, 0)
        CHUNK(2 * t2 + 1, 1)
    }
#undef CHUNK

    // fold the two k-halves of the row-sum (same shift m==0 in both halves)
    lrun += __shfl_xor(lrun, 32, 64);

    // ---- in-block merge of the two KV halves (plain adds; shared shift m==0) ----
    if (w >= 4) {   // upper half publishes partials; per-lane 128B, chunk-XOR swizzled
        char* ob = ldsb + (w4 * 64 + l) * 128;
        #pragma unroll
        for (int dt = 0; dt < 2; ++dt)
            #pragma unroll
            for (int j = 0; j < 4; ++j) {
                int c = (dt * 4 + j) ^ (l & 7);
                f32x4 v4;
                v4[0] = oacc[dt][j * 4 + 0]; v4[1] = oacc[dt][j * 4 + 1];
                v4[2] = oacc[dt][j * 4 + 2]; v4[3] = oacc[dt][j * 4 + 3];
                *(f32x4*)(ob + c * 16) = v4;
            }
        if (hi == 0)
            *(float*)(ldsb + 32768 + (w4 * 32 + l31) * 4) = lrun;
    }
    __syncthreads();
    if (w < 4) {    // lower half merges + writes
        float l2 = *(const float*)(ldsb + 32768 + (w4 * 32 + l31) * 4);
        float inv = 1.f / (lrun + l2);
        const int b = bh >> 3, h = bh & 7;
        const int s = qw + l31;
        unsigned short* dst = Og + ((size_t)(b * 4096 + s)) * 512 + h * 64;
        const char* ob = ldsb + (w4 * 64 + l) * 128;
        #pragma unroll
        for (int dt = 0; dt < 2; ++dt)
            #pragma unroll
            for (int j = 0; j < 4; ++j) {
                int c = (dt * 4 + j) ^ (l & 7);
                f32x4 o2 = *(const f32x4*)(ob + c * 16);
                int d0 = dt * 32 + j * 8 + hi * 4;
                u16x4 v4;
                v4.x = f2bf((oacc[dt][j * 4 + 0] + o2[0]) * inv);
                v4.y = f2bf((oacc[dt][j * 4 + 1] + o2[1]) * inv);
                v4.z = f2bf((oacc[dt][j * 4 + 2] + o2[2]) * inv);
                v4.w = f2bf((oacc[dt][j * 4 + 3] + o2[3]) * inv);
                *(u16x4*)(dst + d0) = v4;
            }
    }
}

extern "C" void kernel_launch(void* const* d_in, const int* in_sizes, int n_in,
                              void* d_out, int out_size, void* d_ws, size_t ws_size,
                              hipStream_t stream)
{
    const float* x  = (const float*)d_in[0];
    const float* Wv = (const float*)d_in[1];
    const float* bv = (const float*)d_in[2];
    const float* Wk = (const float*)d_in[3];
    const float* bk = (const float*)d_in[4];
    const float* Wq = (const float*)d_in[5];
    const float* bq = (const float*)d_in[6];
    const float* Wo = (const float*)d_in[7];
    const float* bo = (const float*)d_in[8];
    float* out = (float*)d_out;

    char* p = (char*)d_ws;
    unsigned short* xb   = (unsigned short*)p; p += (size_t)8192 * 512 * 2;   // x bf16; reused as attn-out
    unsigned short* wqkv = (unsigned short*)p; p += (size_t)1536 * 512 * 2;
    unsigned short* wob  = (unsigned short*)p; p += (size_t)512 * 512 * 2;
    unsigned short* qa   = (unsigned short*)p; p += (size_t)16 * 4096 * 64 * 2;
    unsigned short* ka   = (unsigned short*)p; p += (size_t)16 * 4096 * 64 * 2;
    unsigned short* vta  = (unsigned short*)p; p += (size_t)16 * 4096 * 64 * 2;
    unsigned short* ao   = xb;   // xb is dead after QKV gemm

    cvt_kernel<<<2048, 256, 0, stream>>>(x, Wq, Wk, Wv, Wo, xb, wqkv, wob);

    dim3 gq(12, 64);   // N=1536, M=8192
    gemm_bt<<<gq, 256, 0, stream>>>(xb, wqkv, bq, bk, bv, qa, ka, vta);

    attn_kernel<<<512, 512, 0, stream>>>(qa, ka, vta, ao);

    dim3 go(4, 128);   // N=512 (128-tiles), M=8192 (64-tiles)
    gemm_o<<<go, 256, 0, stream>>>(ao, wob, bo, out);
}

// Round 11
// 121.482 us; speedup vs baseline: 1.1132x; 1.1132x over previous
//
#include <hip/hip_runtime.h>

// MultiHeadAttention: B=2, S=4096, E=512, H=8, D=64
// cvt(fp32->bf16, float4) -> QKV gemm (q pre-scaled by log2e/sqrt(512)) ->
// flash attention (R8-exact: 8 waves, 32x32x16 MFMA, superrow-swizzled K/V LDS,
//                  in-register P via cvtpk+permlane32_swap, fixed-shift softmax,
//                  VALU row-sum, dbuf) ->
// out-proj gemm (64x128 tile, 512 blocks) -> fp32 out.
//
// R9 (ones-MFMA row-sum) and R10 (FZERO pin + vf hoist) both regressed the attn
// loop (R10 via scratch spills: WRITE_SIZE +7MB). R8's loop is the local optimum;
// do not perturb its register schedule.

typedef __bf16 bf16x8 __attribute__((ext_vector_type(8)));
typedef float f32x4 __attribute__((ext_vector_type(4)));
typedef float f32x16 __attribute__((ext_vector_type(16)));
typedef unsigned int u32x4 __attribute__((ext_vector_type(4)));
typedef unsigned short u16x4 __attribute__((ext_vector_type(4)));

union U8 { bf16x8 b; u32x4 q; unsigned short s[8]; };

__device__ __forceinline__ unsigned short f2bf(float f) {
    union { float f; unsigned u; } x; x.f = f;
    unsigned r = x.u + 0x7FFFu + ((x.u >> 16) & 1u);   // RNE
    return (unsigned short)(r >> 16);
}

// packed f32x2 -> bf16x2 (lo -> D[15:0], hi -> D[31:16]) — order verified by R2/R3 pass
__device__ __forceinline__ unsigned cvtpk(float lo, float hi) {
    unsigned d;
    asm("v_cvt_pk_bf16_f32 %0, %1, %2" : "=v"(d) : "v"(lo), "v"(hi));
    return d;
}

#if __has_builtin(__builtin_amdgcn_exp2f)
__device__ __forceinline__ float hexp2(float x) { return __builtin_amdgcn_exp2f(x); }
#else
__device__ __forceinline__ float hexp2(float x) { return exp2f(x); }
#endif

// async global->LDS, 16B per lane. LDS dest is wave-uniform base; HW adds lane*16.
__device__ __forceinline__ void stage16(const void* g, void* lds) {
    __builtin_amdgcn_global_load_lds(
        (const __attribute__((address_space(1))) unsigned*)g,
        (__attribute__((address_space(3))) unsigned*)lds, 16, 0, 0);
}

__device__ __forceinline__ f32x4 mfma16(bf16x8 a, bf16x8 b, f32x4 c) {
    return __builtin_amdgcn_mfma_f32_16x16x32_bf16(a, b, c, 0, 0, 0);
}
__device__ __forceinline__ f32x16 mfma32(bf16x8 a, bf16x8 b, f32x16 c) {
    return __builtin_amdgcn_mfma_f32_32x32x16_bf16(a, b, c, 0, 0, 0);
}

// ---------------- convert fp32 -> bf16 (x, Wq|Wk|Wv packed, Wo), float4 ----------------
__global__ __launch_bounds__(256) void cvt_kernel(
    const float* __restrict__ x, const float* __restrict__ wq, const float* __restrict__ wk,
    const float* __restrict__ wv, const float* __restrict__ wo,
    unsigned short* __restrict__ xb, unsigned short* __restrict__ wqkv,
    unsigned short* __restrict__ wob)
{
    const int NX = 8192 * 512 / 4, NW = 512 * 512 / 4;   // in float4 units
    const int total = NX + 4 * NW;
    for (int i = blockIdx.x * 256 + threadIdx.x; i < total; i += gridDim.x * 256) {
        float4 v; unsigned short* dst;
        if (i < NX) {
            v = ((const float4*)x)[i]; dst = xb + i * 4;
        } else if (i < NX + 3 * NW) {
            int j = i - NX; int p = j / NW; int r = j - p * NW;
            const float* w = (p == 0) ? wq : (p == 1) ? wk : wv;
            v = ((const float4*)w)[r]; dst = wqkv + j * 4;
        } else {
            int j = i - NX - 3 * NW;
            v = ((const float4*)wo)[j]; dst = wob + j * 4;
        }
        u16x4 o;
        o.x = f2bf(v.x); o.y = f2bf(v.y); o.z = f2bf(v.z); o.w = f2bf(v.w);
        *(u16x4*)dst = o;
    }
}

// ---------------- QKV GEMM C = A @ Bw^T (+bias); A:[8192][512], Bw:[1536][512] bf16 ----------------
// scatter: q (pre-scaled by log2e/sqrt(512)) [bh][s][d], k [bh][s][d], vt [bh][d][s]
__global__ __launch_bounds__(256) void gemm_bt(
    const unsigned short* __restrict__ A, const unsigned short* __restrict__ Bw,
    const float* __restrict__ bias0, const float* __restrict__ bias1, const float* __restrict__ bias2,
    unsigned short* __restrict__ qo, unsigned short* __restrict__ ko, unsigned short* __restrict__ vto)
{
    __shared__ unsigned short Al[128 * 64];
    __shared__ unsigned short Bl[128 * 64];
    const int tid = threadIdx.x;
    const int l = tid & 63, w = tid >> 6;
    const int l15 = l & 15, g = l >> 4;
    const int m0 = blockIdx.y * 128, n0 = blockIdx.x * 128;
    const int mo = (w >> 1) * 64, no = (w & 1) * 64;
    f32x4 acc[4][4] = {};

    for (int k0 = 0; k0 < 512; k0 += 64) {
        __syncthreads();
        #pragma unroll
        for (int i = 0; i < 4; ++i) {
            int off = i * 4096 + w * 1024 + l * 16;
            int row = off >> 7;
            int c = (l & 7) ^ (row & 7);
            stage16(A + (m0 + row) * 512 + k0 + c * 8, (char*)Al + i * 4096 + w * 1024);
            stage16(Bw + (n0 + row) * 512 + k0 + c * 8, (char*)Bl + i * 4096 + w * 1024);
        }
        __syncthreads();
        #pragma unroll
        for (int ks = 0; ks < 2; ++ks) {
            U8 af[4];
            #pragma unroll
            for (int mt = 0; mt < 4; ++mt) {
                int row = mo + mt * 16 + l15;
                int c = (ks * 4 + g) ^ (row & 7);
                af[mt].q = *(const u32x4*)((const char*)Al + row * 128 + c * 16);
            }
            #pragma unroll
            for (int nt = 0; nt < 4; ++nt) {
                int row = no + nt * 16 + l15;
                int c = (ks * 4 + g) ^ (row & 7);
                U8 bf; bf.q = *(const u32x4*)((const char*)Bl + row * 128 + c * 16);
                #pragma unroll
                for (int mt = 0; mt < 4; ++mt)
                    acc[mt][nt] = mfma16(af[mt].b, bf.b, acc[mt][nt]);
            }
        }
    }

    const float QSC = 0.06375871897178588f;      // log2(e)/sqrt(512)
    #pragma unroll
    for (int nt = 0; nt < 4; ++nt) {
        int n = n0 + no + nt * 16 + l15;
        int proj = n >> 9, nn = n & 511;
        int h = nn >> 6, d = nn & 63;
        const float* bp = (proj == 0) ? bias0 : (proj == 1) ? bias1 : bias2;
        float bv_ = bp[nn];
        #pragma unroll
        for (int mt = 0; mt < 4; ++mt) {
            int m = m0 + mo + mt * 16 + g * 4;
            int bb = m >> 12, s = m & 4095;
            if (proj == 0) {
                unsigned short* dst = qo + ((bb * 8 + h) * 4096 + s) * 64 + d;
                #pragma unroll
                for (int r = 0; r < 4; ++r)
                    dst[r * 64] = f2bf((acc[mt][nt][r] + bv_) * QSC);
            } else if (proj == 1) {
                unsigned short* dst = ko + ((bb * 8 + h) * 4096 + s) * 64 + d;
                #pragma unroll
                for (int r = 0; r < 4; ++r)
                    dst[r * 64] = f2bf(acc[mt][nt][r] + bv_);
            } else {
                u16x4 v4;
                v4.x = f2bf(acc[mt][nt][0] + bv_);
                v4.y = f2bf(acc[mt][nt][1] + bv_);
                v4.z = f2bf(acc[mt][nt][2] + bv_);
                v4.w = f2bf(acc[mt][nt][3] + bv_);
                *(u16x4*)(vto + ((bb * 8 + h) * 64 + d) * 4096 + s) = v4;
            }
        }
    }
}

// ---------------- out-proj GEMM: out = ao @ Wo^T + bo; 64x128 tile, grid 4x128 ----------------
__global__ __launch_bounds__(256) void gemm_o(
    const unsigned short* __restrict__ A, const unsigned short* __restrict__ Bw,
    const float* __restrict__ bias, float* __restrict__ outf)
{
    __shared__ unsigned short Al[64 * 64];    // 8KB
    __shared__ unsigned short Bl[128 * 64];   // 16KB
    const int tid = threadIdx.x;
    const int l = tid & 63, w = tid >> 6;
    const int l15 = l & 15, g = l >> 4;
    const int m0 = blockIdx.y * 64, n0 = blockIdx.x * 128;
    const int mo = (w >> 1) * 32, no = (w & 1) * 64;
    f32x4 acc[2][4] = {};

    for (int k0 = 0; k0 < 512; k0 += 64) {
        __syncthreads();
        #pragma unroll
        for (int i = 0; i < 2; ++i) {
            int jj = w * 2 + i;
            int off = jj * 1024 + l * 16;
            int row = off >> 7;
            int c = (l & 7) ^ (row & 7);
            stage16(A + (m0 + row) * 512 + k0 + c * 8, (char*)Al + jj * 1024);
        }
        #pragma unroll
        for (int i = 0; i < 4; ++i) {
            int jj = w * 4 + i;
            int off = jj * 1024 + l * 16;
            int row = off >> 7;
            int c = (l & 7) ^ (row & 7);
            stage16(Bw + (n0 + row) * 512 + k0 + c * 8, (char*)Bl + jj * 1024);
        }
        __syncthreads();
        #pragma unroll
        for (int ks = 0; ks < 2; ++ks) {
            U8 af[2];
            #pragma unroll
            for (int mt = 0; mt < 2; ++mt) {
                int row = mo + mt * 16 + l15;
                int c = (ks * 4 + g) ^ (row & 7);
                af[mt].q = *(const u32x4*)((const char*)Al + row * 128 + c * 16);
            }
            #pragma unroll
            for (int nt = 0; nt < 4; ++nt) {
                int row = no + nt * 16 + l15;
                int c = (ks * 4 + g) ^ (row & 7);
                U8 bf; bf.q = *(const u32x4*)((const char*)Bl + row * 128 + c * 16);
                #pragma unroll
                for (int mt = 0; mt < 2; ++mt)
                    acc[mt][nt] = mfma16(af[mt].b, bf.b, acc[mt][nt]);
            }
        }
    }
    #pragma unroll
    for (int nt = 0; nt < 4; ++nt) {
        int n = n0 + no + nt * 16 + l15;
        float bv_ = bias[n];
        #pragma unroll
        for (int mt = 0; mt < 2; ++mt) {
            int m = m0 + mo + mt * 16 + g * 4;
            float* dst = outf + (size_t)m * 512 + n;
            #pragma unroll
            for (int r = 0; r < 4; ++r)
                dst[(size_t)r * 512] = acc[mt][nt][r] + bv_;
        }
    }
}

// ---------------- flash attention (R8-exact): 8 waves, 32x32x16, superrow-swizzled LDS ----------------
// grid 512. wave w: half hb=w>>2 (KV range [hb*2048,+2048)), q-group w4=w&3 (32 q-rows).
// LDS per parity per half: [K 8KB][V 8KB]; 2 parities x 2 halves = 64KB.
// Tile [64 rows][128B]; swizzle: s_phys = ((row&1)*8 + chunkcol) ^ ((row>>1)&15),
// same involution on stage-source and read -> conflict-free b128 (verified R6: 65K conflicts).
// P pack via cvtpk+permlane32_swap (verified R3). Fixed-shift softmax (m==0, verified R8).
__global__ __launch_bounds__(512, 4) void attn_kernel(
    const unsigned short* __restrict__ Qg, const unsigned short* __restrict__ Kg,
    const unsigned short* __restrict__ Vtg, unsigned short* __restrict__ Og)
{
    __shared__ __align__(16) char ldsb[65536];
    const int tid = threadIdx.x;
    const int l = tid & 63, w = tid >> 6;
    const int l31 = l & 31, hi = l >> 5;
    const int hb = w >> 2, w4 = w & 3;

    // XCD swizzle: 2 whole heads per XCD.
    const int xcd = blockIdx.x & 7, idx = blockIdx.x >> 3;
    const int bh = xcd * 2 + (idx >> 5), qb = idx & 31;

    const unsigned short* qh = Qg + bh * 4096 * 64;
    const char* khb = (const char*)(Kg + (size_t)bh * 4096 * 64);
    const char* vhb = (const char*)(Vtg + (size_t)bh * 64 * 4096);
    const int qw = qb * 128 + w4 * 32;

    // Q B-frags (log2-domain pre-scaled): Qf[ds] elem i = Q[qw+l31][ds*16 + 8*hi + i]
    U8 Qf[4];
    #pragma unroll
    for (int ds_ = 0; ds_ < 4; ++ds_)
        Qf[ds_].q = *(const u32x4*)(qh + (qw + l31) * 64 + ds_ * 16 + hi * 8);

    // frag-read lane offsets (same formula for K and V): frag row = base32 + l31,
    // chunk-col = 2*j + hi; superrow R = (row>>1), swizzled slot, +hb tile select.
    int rd[4];
    #pragma unroll
    for (int j = 0; j < 4; ++j) {
        int sl = ((l31 & 1) << 3) + j * 2 + hi;
        int sp = sl ^ (l31 >> 1);
        rd[j] = hb * 16384 + (l31 >> 1) * 256 + sp * 16;
    }

    // stage source pointers: lane covers LDS tile byte q = jj*1024 + l*16.
    // decode: R=q>>8, sp=(q>>4)&15, sl=sp^(R&15), row=2R+(sl>>3), c=sl&7
    const char* ksrc0; const char* ksrc1; const char* vsrc0; const char* vsrc1;
    {
        int q0 = (w4 * 2 + 0) * 1024 + l * 16;
        int q1 = (w4 * 2 + 1) * 1024 + l * 16;
        int R0 = q0 >> 8, sl0 = ((q0 >> 4) & 15) ^ (R0 & 15);
        int R1 = q1 >> 8, sl1 = ((q1 >> 4) & 15) ^ (R1 & 15);
        int row0 = 2 * R0 + (sl0 >> 3), c0 = sl0 & 7;
        int row1 = 2 * R1 + (sl1 >> 3), c1 = sl1 & 7;
        ksrc0 = khb + (size_t)(hb * 2048 + row0) * 128 + c0 * 16;
        ksrc1 = khb + (size_t)(hb * 2048 + row1) * 128 + c1 * 16;
        vsrc0 = vhb + (size_t)row0 * 8192 + hb * 4096 + c0 * 16;
        vsrc1 = vhb + (size_t)row1 * 8192 + hb * 4096 + c1 * 16;
    }

    f32x16 oacc[2] = {};   // [dt] : O^T[d = dt*32 + crow][q = l31]
    float lrun = 0.f;      // own-half partial row-sum (shift m==0)

    // prologue: stage chunk 0 into parity-0 buffers
    stage16(ksrc0, ldsb + hb * 16384 + (w4 * 2 + 0) * 1024);
    stage16(ksrc1, ldsb + hb * 16384 + (w4 * 2 + 1) * 1024);
    stage16(vsrc0, ldsb + hb * 16384 + 8192 + (w4 * 2 + 0) * 1024);
    stage16(vsrc1, ldsb + hb * 16384 + 8192 + (w4 * 2 + 1) * 1024);
    ksrc0 += 8192; ksrc1 += 8192; vsrc0 += 128; vsrc1 += 128;
    __syncthreads();

#define CHUNK(T_, PAR_) {                                                          \
    if ((T_) != 31) {                                                              \
        stage16(ksrc0, ldsb + (1 - (PAR_)) * 32768 + hb * 16384 + (w4 * 2 + 0) * 1024); \
        stage16(ksrc1, ldsb + (1 - (PAR_)) * 32768 + hb * 16384 + (w4 * 2 + 1) * 1024); \
        stage16(vsrc0, ldsb + (1 - (PAR_)) * 32768 + hb * 16384 + 8192 + (w4 * 2 + 0) * 1024); \
        stage16(vsrc1, ldsb + (1 - (PAR_)) * 32768 + hb * 16384 + 8192 + (w4 * 2 + 1) * 1024); \
    }                                                                              \
    ksrc0 += 8192; ksrc1 += 8192; vsrc0 += 128; vsrc1 += 128;                      \
    f32x16 et[2]; { f32x16 z = {}; et[0] = z; et[1] = z; }                         \
    __builtin_amdgcn_s_setprio(1);                                                 \
    _Pragma("unroll")                                                              \
    for (int ds_ = 0; ds_ < 4; ++ds_) {                                            \
        U8 kf0, kf1;                                                               \
        kf0.q = *(const u32x4*)(ldsb + (PAR_) * 32768 + rd[ds_]);                  \
        kf1.q = *(const u32x4*)(ldsb + (PAR_) * 32768 + 4096 + rd[ds_]);           \
        et[0] = mfma32(kf0.b, Qf[ds_].b, et[0]);                                   \
        et[1] = mfma32(kf1.b, Qf[ds_].b, et[1]);                                   \
    }                                                                              \
    __builtin_amdgcn_s_setprio(0);                                                 \
    float rs = 0.f;                                                                \
    _Pragma("unroll")                                                              \
    for (int ks = 0; ks < 4; ++ks) {                                               \
        const int mt_ = ks >> 1, r0_ = (ks & 1) * 8;                               \
        float p0 = hexp2(et[mt_][r0_ + 0]);                                        \
        float p1 = hexp2(et[mt_][r0_ + 1]);                                        \
        float p2 = hexp2(et[mt_][r0_ + 2]);                                        \
        float p3 = hexp2(et[mt_][r0_ + 3]);                                        \
        float p4 = hexp2(et[mt_][r0_ + 4]);                                        \
        float p5 = hexp2(et[mt_][r0_ + 5]);                                        \
        float p6 = hexp2(et[mt_][r0_ + 6]);                                        \
        float p7 = hexp2(et[mt_][r0_ + 7]);                                        \
        rs += ((p0 + p1) + (p2 + p3)) + ((p4 + p5) + (p6 + p7));                   \
        unsigned X0 = cvtpk(p0, p1), X1 = cvtpk(p2, p3);                           \
        unsigned Y0 = cvtpk(p4, p5), Y1 = cvtpk(p6, p7);                           \
        asm volatile("v_permlane32_swap_b32 %0, %1" : "+v"(X0), "+v"(Y0));         \
        asm volatile("v_permlane32_swap_b32 %0, %1" : "+v"(X1), "+v"(Y1));         \
        U8 pb_; pb_.q.x = X0; pb_.q.y = X1; pb_.q.z = Y0; pb_.q.w = Y1;            \
        U8 vf0, vf1;                                                               \
        vf0.q = *(const u32x4*)(ldsb + (PAR_) * 32768 + 8192 + rd[ks]);            \
        vf1.q = *(const u32x4*)(ldsb + (PAR_) * 32768 + 8192 + 4096 + rd[ks]);     \
        __builtin_amdgcn_s_setprio(1);                                             \
        oacc[0] = mfma32(vf0.b, pb_.b, oacc[0]);                                   \
        oacc[1] = mfma32(vf1.b, pb_.b, oacc[1]);                                   \
        __builtin_amdgcn_s_setprio(0);                                             \
    }                                                                              \
    lrun += rs;   /* own-half partial; cross-half summed after loop */             \
    __syncthreads();                                                               \
}

    #pragma unroll 1
    for (int t2 = 0; t2 < 16; ++t2) {
        CHUNK(2 * t2, 0)
        CHUNK(2 * t2 + 1, 1)
    }
#undef CHUNK

    // fold the two k-halves of the row-sum (same shift m==0 in both halves)
    lrun += __shfl_xor(lrun, 32, 64);

    // ---- in-block merge of the two KV halves (plain adds; shared shift m==0) ----
    if (w >= 4) {   // upper half publishes partials; per-lane 128B, chunk-XOR swizzled
        char* ob = ldsb + (w4 * 64 + l) * 128;
        #pragma unroll
        for (int dt = 0; dt < 2; ++dt)
            #pragma unroll
            for (int j = 0; j < 4; ++j) {
                int c = (dt * 4 + j) ^ (l & 7);
                f32x4 v4;
                v4[0] = oacc[dt][j * 4 + 0]; v4[1] = oacc[dt][j * 4 + 1];
                v4[2] = oacc[dt][j * 4 + 2]; v4[3] = oacc[dt][j * 4 + 3];
                *(f32x4*)(ob + c * 16) = v4;
            }
        if (hi == 0)
            *(float*)(ldsb + 32768 + (w4 * 32 + l31) * 4) = lrun;
    }
    __syncthreads();
    if (w < 4) {    // lower half merges + writes
        float l2 = *(const float*)(ldsb + 32768 + (w4 * 32 + l31) * 4);
        float inv = 1.f / (lrun + l2);
        const int b = bh >> 3, h = bh & 7;
        const int s = qw + l31;
        unsigned short* dst = Og + ((size_t)(b * 4096 + s)) * 512 + h * 64;
        const char* ob = ldsb + (w4 * 64 + l) * 128;
        #pragma unroll
        for (int dt = 0; dt < 2; ++dt)
            #pragma unroll
            for (int j = 0; j < 4; ++j) {
                int c = (dt * 4 + j) ^ (l & 7);
                f32x4 o2 = *(const f32x4*)(ob + c * 16);
                int d0 = dt * 32 + j * 8 + hi * 4;
                u16x4 v4;
                v4.x = f2bf((oacc[dt][j * 4 + 0] + o2[0]) * inv);
                v4.y = f2bf((oacc[dt][j * 4 + 1] + o2[1]) * inv);
                v4.z = f2bf((oacc[dt][j * 4 + 2] + o2[2]) * inv);
                v4.w = f2bf((oacc[dt][j * 4 + 3] + o2[3]) * inv);
                *(u16x4*)(dst + d0) = v4;
            }
    }
}

extern "C" void kernel_launch(void* const* d_in, const int* in_sizes, int n_in,
                              void* d_out, int out_size, void* d_ws, size_t ws_size,
                              hipStream_t stream)
{
    const float* x  = (const float*)d_in[0];
    const float* Wv = (const float*)d_in[1];
    const float* bv = (const float*)d_in[2];
    const float* Wk = (const float*)d_in[3];
    const float* bk = (const float*)d_in[4];
    const float* Wq = (const float*)d_in[5];
    const float* bq = (const float*)d_in[6];
    const float* Wo = (const float*)d_in[7];
    const float* bo = (const float*)d_in[8];
    float* out = (float*)d_out;

    char* p = (char*)d_ws;
    unsigned short* xb   = (unsigned short*)p; p += (size_t)8192 * 512 * 2;   // x bf16; reused as attn-out
    unsigned short* wqkv = (unsigned short*)p; p += (size_t)1536 * 512 * 2;
    unsigned short* wob  = (unsigned short*)p; p += (size_t)512 * 512 * 2;
    unsigned short* qa   = (unsigned short*)p; p += (size_t)16 * 4096 * 64 * 2;
    unsigned short* ka   = (unsigned short*)p; p += (size_t)16 * 4096 * 64 * 2;
    unsigned short* vta  = (unsigned short*)p; p += (size_t)16 * 4096 * 64 * 2;
    unsigned short* ao   = xb;   // xb is dead after QKV gemm

    cvt_kernel<<<2048, 256, 0, stream>>>(x, Wq, Wk, Wv, Wo, xb, wqkv, wob);

    dim3 gq(12, 64);   // N=1536, M=8192
    gemm_bt<<<gq, 256, 0, stream>>>(xb, wqkv, bq, bk, bv, qa, ka, vta);

    attn_kernel<<<512, 512, 0, stream>>>(qa, ka, vta, ao);

    dim3 go(4, 128);   // N=512 (128-tiles), M=8192 (64-tiles)
    gemm_o<<<go, 256, 0, stream>>>(ao, wob, bo, out);
}